// Round 8
// baseline (52.116 us; speedup 1.0000x reference)
//
#include <hip/hip_runtime.h>
#include <math.h>
#include <float.h>

#define BATCH 128
#define LEN   100000
#define BPR   8                  // blocks per row
#define CHUNK (LEN / BPR)        // 12500 elements per block
#define VPS   (CHUNK / 4)        // 3125 float4 vectors per block
#define T     512                // threads per block (8 waves)
#define NFULL 6                  // full groups of T vectors
#define TAILV (VPS - NFULL * T)  // 53 vectors in tail group
#define NG    (NFULL + 1)        // 7 groups -> mask bits 0..27
#define NSEG  (BATCH * BPR)      // 1024 table entries

// ---------- workspace layout ----------
struct WS {
    int*   lt_tab; int* ht_tab; int* lp_tab; int* hp_tab;   // [NSEG]
    float* bce_blk; float* sm_blk;                          // [NSEG]
    float* cmin; float* cmax;                               // [NSEG]
    float* wmn; float* wmx;                                 // [2*BATCH]
};

static inline WS ws_layout(void* d_ws) {
    WS w;
    w.lt_tab  = (int*)d_ws;
    w.ht_tab  = w.lt_tab + NSEG;
    w.lp_tab  = w.ht_tab + NSEG;
    w.hp_tab  = w.lp_tab + NSEG;
    w.bce_blk = (float*)(w.hp_tab + NSEG);
    w.sm_blk  = w.bce_blk + NSEG;
    w.cmin    = w.sm_blk  + NSEG;
    w.cmax    = w.cmin    + NSEG;
    w.wmn     = w.cmax    + NSEG;
    w.wmx     = w.wmn     + 2 * BATCH;
    return w;
}

// ---------- main fused pass ----------
// The CLEAN one-generation experiment: R4's 8-wave block code verbatim,
// 1024 blocks x 8 waves = 8192 waves = exactly 32/CU, uniform, no tail.
// R5's poison (launch_bounds min-waves -> spills) and R7's poison (16-wave
// blocks + per-stripe reductions) both excluded. cmin/cmax at block
// granularity, exactly as R4.

__global__ __launch_bounds__(T) void k_main(
        const float* __restrict__ sig,
        const float* __restrict__ pred,
        const float* __restrict__ targ,
        int* __restrict__ lt_tab, int* __restrict__ ht_tab,
        int* __restrict__ lp_tab, int* __restrict__ hp_tab,
        float* __restrict__ bce_blk, float* __restrict__ sm_blk,
        float* __restrict__ cmin_tab, float* __restrict__ cmax_tab) {
    const int b   = blockIdx.y;
    const int blk = blockIdx.x;          // 0..BPR-1
    const int tid = threadIdx.x;
    const size_t row = (size_t)b * LEN;
    const float* prow = pred + row;
    const float* trow = targ + row;
    const float* srow = sig  + row;
    const int base = blk * CHUNK;
    const int w = tid >> 6, lane = tid & 63;

    float bce = 0.0f, sm = 0.0f;
    float cmn = FLT_MAX, cmx = -FLT_MAX;
    unsigned tmask = 0u, pmask = 0u;     // 28 bits used (7 groups x 4)

    #pragma unroll
    for (int k = 0; k < NG; ++k) {
        const bool act = (k < NFULL) || (tid < TAILV);
        if (act) {
            const int l0 = base + (tid + k * T) * 4;
            const float4 p4 = *reinterpret_cast<const float4*>(prow + l0);
            const float4 t4 = *reinterpret_cast<const float4*>(trow + l0);
            const float4 s4 = *reinterpret_cast<const float4*>(srow + l0);
            float sg0, sg1, sg2, sg3;
            #define ONE_ELEM(pp, tt, ss, sgv, BIT) { \
                const float ap = fabsf(pp); \
                const float ee = __expf(-ap); \
                const float zz = 1.0f + ee; \
                const float rr = __builtin_amdgcn_rcpf(zz); \
                bce += fmaxf(pp, 0.0f) - (pp) * (tt) + __logf(zz); \
                sgv = ((pp) >= 0.0f) ? rr : ee * rr; \
                tmask |= ((tt) > 0.5f) ? (1u << (BIT)) : 0u; \
                pmask |= ((pp) > 0.0f) ? (1u << (BIT)) : 0u; \
                cmn = fminf(cmn, (ss)); cmx = fmaxf(cmx, (ss)); }
            ONE_ELEM(p4.x, t4.x, s4.x, sg0, 4 * k + 0)
            ONE_ELEM(p4.y, t4.y, s4.y, sg1, 4 * k + 1)
            ONE_ELEM(p4.z, t4.z, s4.z, sg2, 4 * k + 2)
            ONE_ELEM(p4.w, t4.w, s4.w, sg3, 4 * k + 3)
            #undef ONE_ELEM
            sm += fabsf(sg1 - sg0) + fabsf(sg2 - sg1) + fabsf(sg3 - sg2);
            const float prev3 = __shfl_up(sg3, 1);   // lane-1's sg3
            if (lane == 0) {
                if (l0 > 0) {                        // wave boundary: recompute
                    const float pp = prow[l0 - 1];
                    const float ee = __expf(-fabsf(pp));
                    const float rr = __builtin_amdgcn_rcpf(1.0f + ee);
                    const float sp = (pp >= 0.0f) ? rr : ee * rr;
                    sm += fabsf(sg0 - sp);
                }
            } else {
                sm += fabsf(sg0 - prev3);
            }
        }
    }

    // ---- decode index masks (bit position monotone in element index) ----
    int lt = LEN, ht = -1, lp = LEN, hp = -1;
    if (tmask) {
        const int f = __ffs(tmask) - 1;
        const int h = 31 - __clz((int)tmask);
        lt = base + (tid + (f >> 2) * T) * 4 + (f & 3);
        ht = base + (tid + (h >> 2) * T) * 4 + (h & 3);
    }
    if (pmask) {
        const int f = __ffs(pmask) - 1;
        const int h = 31 - __clz((int)pmask);
        lp = base + (tid + (f >> 2) * T) * 4 + (f & 3);
        hp = base + (tid + (h >> 2) * T) * 4 + (h & 3);
    }

    // ---- block-wide wave reductions ----
    #pragma unroll
    for (int o = 32; o > 0; o >>= 1) {
        bce += __shfl_xor(bce, o);
        sm  += __shfl_xor(sm,  o);
        cmn  = fminf(cmn, __shfl_xor(cmn, o));
        cmx  = fmaxf(cmx, __shfl_xor(cmx, o));
        lt   = min(lt, __shfl_xor(lt, o));
        ht   = max(ht, __shfl_xor(ht, o));
        lp   = min(lp, __shfl_xor(lp, o));
        hp   = max(hp, __shfl_xor(hp, o));
    }

    __shared__ float s_bce[8], s_sm[8], s_mn[8], s_mx[8];
    __shared__ int   s_lt[8], s_ht[8], s_lp[8], s_hp[8];
    if (lane == 0) {
        s_bce[w] = bce; s_sm[w] = sm; s_mn[w] = cmn; s_mx[w] = cmx;
        s_lt[w] = lt; s_ht[w] = ht; s_lp[w] = lp; s_hp[w] = hp;
    }
    __syncthreads();
    if (tid == 0) {
        float B = 0.0f, S = 0.0f, MN = FLT_MAX, MX = -FLT_MAX;
        int LT = LEN, HT = -1, LP = LEN, HP = -1;
        #pragma unroll
        for (int i = 0; i < 8; ++i) {
            B += s_bce[i]; S += s_sm[i];
            MN = fminf(MN, s_mn[i]); MX = fmaxf(MX, s_mx[i]);
            LT = min(LT, s_lt[i]); HT = max(HT, s_ht[i]);
            LP = min(LP, s_lp[i]); HP = max(HP, s_hp[i]);
        }
        const int e = b * BPR + blk;
        bce_blk[e] = B; sm_blk[e] = S;
        cmin_tab[e] = MN; cmax_tab[e] = MX;
        lt_tab[e] = LT; ht_tab[e] = HT;
        lp_tab[e] = LP; hp_tab[e] = HP;
    }
}

// ---------- windowed min/max per (row, which) ----------

__global__ __launch_bounds__(T) void k_rows(
        const float* __restrict__ sig,
        const int* __restrict__ lt_tab, const int* __restrict__ ht_tab,
        const int* __restrict__ lp_tab, const int* __restrict__ hp_tab,
        const float* __restrict__ cmin_tab, const float* __restrict__ cmax_tab,
        float* __restrict__ wmn, float* __restrict__ wmx) {
    const int b     = blockIdx.x;
    const int which = blockIdx.y;          // 0 = target window, 1 = pred window
    const int tid   = threadIdx.x;
    const int* lo_tab = which ? lp_tab : lt_tab;
    const int* hi_tab = which ? hp_tab : ht_tab;

    int lo = LEN, hi = -1;
    if (tid < BPR) { lo = lo_tab[b * BPR + tid]; hi = hi_tab[b * BPR + tid]; }
    #pragma unroll
    for (int o = 32; o > 0; o >>= 1) {
        lo = min(lo, __shfl_xor(lo, o));
        hi = max(hi, __shfl_xor(hi, o));
    }
    __shared__ int s_lo, s_hi;
    if (tid == 0) { s_lo = lo; s_hi = hi; }
    __syncthreads();
    lo = s_lo; hi = s_hi;

    float mn = FLT_MAX, mx = -FLT_MAX;
    if (lo < LEN) {
        const float* srow = sig + (size_t)b * LEN;
        const int cl = lo / CHUNK, ch = hi / CHUNK;
        const int e1 = (cl == ch) ? hi : cl * CHUNK + CHUNK - 1;
        for (int l = lo + tid; l <= e1; l += T) {
            const float x = srow[l]; mn = fminf(mn, x); mx = fmaxf(mx, x);
        }
        if (ch > cl) {
            for (int l = ch * CHUNK + tid; l <= hi; l += T) {
                const float x = srow[l]; mn = fminf(mn, x); mx = fmaxf(mx, x);
            }
            const float* cmin_row = cmin_tab + b * BPR;
            const float* cmax_row = cmax_tab + b * BPR;
            for (int c = cl + 1 + tid; c < ch; c += T) {
                mn = fminf(mn, cmin_row[c]); mx = fmaxf(mx, cmax_row[c]);
            }
        }
    }
    #pragma unroll
    for (int o = 32; o > 0; o >>= 1) {
        mn = fminf(mn, __shfl_xor(mn, o));
        mx = fmaxf(mx, __shfl_xor(mx, o));
    }
    __shared__ float sh_mn[8], sh_mx[8];
    const int w = tid >> 6, lane = tid & 63;
    if (lane == 0) { sh_mn[w] = mn; sh_mx[w] = mx; }
    __syncthreads();
    if (tid == 0) {
        float MN = FLT_MAX, MX = -FLT_MAX;
        #pragma unroll
        for (int i = 0; i < 8; ++i) {
            MN = fminf(MN, sh_mn[i]); MX = fmaxf(MX, sh_mx[i]);
        }
        if (lo >= LEN) { MN = 1e30f; MX = -1e30f; }   // invalid marker: MX < MN
        wmn[which * BATCH + b] = MN;
        wmx[which * BATCH + b] = MX;
    }
}

// ---------- final combine ----------

__global__ void k_combine(const float* __restrict__ bce_blk,
                          const float* __restrict__ sm_blk,
                          const float* __restrict__ wmn,
                          const float* __restrict__ wmx,
                          float* __restrict__ out) {
    const int tid = threadIdx.x;
    float acc_b = 0.0f, acc_s = 0.0f, acc_a = 0.0f;
    for (int i = tid; i < NSEG; i += 256) { acc_b += bce_blk[i]; acc_s += sm_blk[i]; }
    if (tid < BATCH) {
        const float tmn = wmn[tid],          tmx = wmx[tid];
        const float pmn = wmn[BATCH + tid],  pmx = wmx[BATCH + tid];
        if (tmx >= tmn && pmx >= pmn) {      // both windows valid
            const float ta = tmx - tmn;
            const float pa = pmx - pmn;
            const float d  = fabsf(ta - pa);
            acc_a = (ta > 1e-6f) ? d / (ta + 1e-6f) : d;
        }
    }
    #pragma unroll
    for (int o = 32; o > 0; o >>= 1) {
        acc_b += __shfl_xor(acc_b, o);
        acc_s += __shfl_xor(acc_s, o);
        acc_a += __shfl_xor(acc_a, o);
    }
    __shared__ float sb[4], ss[4], sa[4];
    const int w = tid >> 6, lane = tid & 63;
    if (lane == 0) { sb[w] = acc_b; ss[w] = acc_s; sa[w] = acc_a; }
    __syncthreads();
    if (tid == 0) {
        const double B = (double)(sb[0] + sb[1] + sb[2] + sb[3]);
        const double S = (double)(ss[0] + ss[1] + ss[2] + ss[3]);
        const double A = (double)(sa[0] + sa[1] + sa[2] + sa[3]);
        const double bce = B / ((double)BATCH * (double)LEN);
        const double smo = S / ((double)BATCH * (double)(LEN - 1));
        const double amp = A / (double)BATCH;
        out[0] = (float)(1.0 * bce + 0.5 * amp + 0.3 * smo);
    }
}

// ---------- launch ----------

extern "C" void kernel_launch(void* const* d_in, const int* in_sizes, int n_in,
                              void* d_out, int out_size, void* d_ws, size_t ws_size,
                              hipStream_t stream) {
    const float* signals = (const float*)d_in[0];   // (B, 1, L)
    const float* preds   = (const float*)d_in[1];   // (B, L, 1)
    const float* targs   = (const float*)d_in[2];   // (B, L, 1)
    float* out = (float*)d_out;
    WS w = ws_layout(d_ws);

    dim3 gm(BPR, BATCH);   // 1024 blocks x 8 waves = 8192 waves = 1 generation
    k_main<<<gm, T, 0, stream>>>(signals, preds, targs,
                                 w.lt_tab, w.ht_tab, w.lp_tab, w.hp_tab,
                                 w.bce_blk, w.sm_blk, w.cmin, w.cmax);

    dim3 gr(BATCH, 2);
    k_rows<<<gr, T, 0, stream>>>(signals,
                                 w.lt_tab, w.ht_tab, w.lp_tab, w.hp_tab,
                                 w.cmin, w.cmax, w.wmn, w.wmx);

    k_combine<<<1, 256, 0, stream>>>(w.bce_blk, w.sm_blk, w.wmn, w.wmx, out);
}

// Round 9
// 46.203 us; speedup vs baseline: 1.1280x; 1.1280x over previous
//
#include <hip/hip_runtime.h>
#include <math.h>
#include <float.h>

#define BATCH 128
#define LEN   100000
#define BPR   40                 // blocks per row
#define CHUNK (LEN / BPR)        // 2500 elements per block
#define VPS   (CHUNK / 4)        // 625 float4 vectors per block
#define T     512                // threads per block (8 waves)
#define NFULL 1                  // full groups of T vectors
#define TAILV (VPS - NFULL * T)  // 113 vectors in tail group
#define NG    (NFULL + 1)        // 2 groups -> mask bits 0..7
#define NSEG  (BATCH * BPR)      // 5120 table entries

// ---------- workspace layout ----------
struct WS {
    int*   lt_tab; int* ht_tab; int* lp_tab; int* hp_tab;   // [NSEG]
    float* bce_blk; float* sm_blk;                          // [NSEG]
    float* cmin; float* cmax;                               // [NSEG]
    float* wmn; float* wmx;                                 // [2*BATCH]
};

static inline WS ws_layout(void* d_ws) {
    WS w;
    w.lt_tab  = (int*)d_ws;
    w.ht_tab  = w.lt_tab + NSEG;
    w.lp_tab  = w.ht_tab + NSEG;
    w.hp_tab  = w.lp_tab + NSEG;
    w.bce_blk = (float*)(w.hp_tab + NSEG);
    w.sm_blk  = w.bce_blk + NSEG;
    w.cmin    = w.sm_blk  + NSEG;
    w.cmax    = w.cmin    + NSEG;
    w.wmn     = w.cmax    + NSEG;
    w.wmx     = w.wmn     + 2 * BATCH;
    return w;
}

// ---------- main fused pass ----------
// Trend-following step: R0(20 elem/thr)=48.9 -> R4(12)=43.4; R7/R8 showed
// exact-fit grids LOWER occupancy (no backfill). So: 5120 blocks x 512t,
// ~4.9 elems/thread, maximal backfill pool. No fences (R6 poison), no
// launch_bounds min-waves (R5 poison), no stripe machinery (R7 overhead).

__global__ __launch_bounds__(T) void k_main(
        const float* __restrict__ sig,
        const float* __restrict__ pred,
        const float* __restrict__ targ,
        int* __restrict__ lt_tab, int* __restrict__ ht_tab,
        int* __restrict__ lp_tab, int* __restrict__ hp_tab,
        float* __restrict__ bce_blk, float* __restrict__ sm_blk,
        float* __restrict__ cmin_tab, float* __restrict__ cmax_tab) {
    const int b   = blockIdx.y;
    const int blk = blockIdx.x;          // 0..BPR-1
    const int tid = threadIdx.x;
    const size_t row = (size_t)b * LEN;
    const float* prow = pred + row;
    const float* trow = targ + row;
    const float* srow = sig  + row;
    const int base = blk * CHUNK;
    const int w = tid >> 6, lane = tid & 63;

    float bce = 0.0f, sm = 0.0f;
    float cmn = FLT_MAX, cmx = -FLT_MAX;
    unsigned tmask = 0u, pmask = 0u;     // 8 bits used (2 groups x 4)

    #pragma unroll
    for (int k = 0; k < NG; ++k) {
        const bool act = (k < NFULL) || (tid < TAILV);
        if (act) {
            const int l0 = base + (tid + k * T) * 4;
            const float4 p4 = *reinterpret_cast<const float4*>(prow + l0);
            const float4 t4 = *reinterpret_cast<const float4*>(trow + l0);
            const float4 s4 = *reinterpret_cast<const float4*>(srow + l0);
            float sg0, sg1, sg2, sg3;
            #define ONE_ELEM(pp, tt, ss, sgv, BIT) { \
                const float ap = fabsf(pp); \
                const float ee = __expf(-ap); \
                const float zz = 1.0f + ee; \
                const float rr = __builtin_amdgcn_rcpf(zz); \
                bce += fmaxf(pp, 0.0f) - (pp) * (tt) + __logf(zz); \
                sgv = ((pp) >= 0.0f) ? rr : ee * rr; \
                tmask |= ((tt) > 0.5f) ? (1u << (BIT)) : 0u; \
                pmask |= ((pp) > 0.0f) ? (1u << (BIT)) : 0u; \
                cmn = fminf(cmn, (ss)); cmx = fmaxf(cmx, (ss)); }
            ONE_ELEM(p4.x, t4.x, s4.x, sg0, 4 * k + 0)
            ONE_ELEM(p4.y, t4.y, s4.y, sg1, 4 * k + 1)
            ONE_ELEM(p4.z, t4.z, s4.z, sg2, 4 * k + 2)
            ONE_ELEM(p4.w, t4.w, s4.w, sg3, 4 * k + 3)
            #undef ONE_ELEM
            sm += fabsf(sg1 - sg0) + fabsf(sg2 - sg1) + fabsf(sg3 - sg2);
            const float prev3 = __shfl_up(sg3, 1);   // lane-1's sg3
            if (lane == 0) {
                if (l0 > 0) {                        // wave boundary: recompute
                    const float pp = prow[l0 - 1];
                    const float ee = __expf(-fabsf(pp));
                    const float rr = __builtin_amdgcn_rcpf(1.0f + ee);
                    const float sp = (pp >= 0.0f) ? rr : ee * rr;
                    sm += fabsf(sg0 - sp);
                }
            } else {
                sm += fabsf(sg0 - prev3);
            }
        }
    }

    // ---- decode index masks (bit position monotone in element index) ----
    int lt = LEN, ht = -1, lp = LEN, hp = -1;
    if (tmask) {
        const int f = __ffs(tmask) - 1;
        const int h = 31 - __clz((int)tmask);
        lt = base + (tid + (f >> 2) * T) * 4 + (f & 3);
        ht = base + (tid + (h >> 2) * T) * 4 + (h & 3);
    }
    if (pmask) {
        const int f = __ffs(pmask) - 1;
        const int h = 31 - __clz((int)pmask);
        lp = base + (tid + (f >> 2) * T) * 4 + (f & 3);
        hp = base + (tid + (h >> 2) * T) * 4 + (h & 3);
    }

    // ---- block-wide wave reductions ----
    #pragma unroll
    for (int o = 32; o > 0; o >>= 1) {
        bce += __shfl_xor(bce, o);
        sm  += __shfl_xor(sm,  o);
        cmn  = fminf(cmn, __shfl_xor(cmn, o));
        cmx  = fmaxf(cmx, __shfl_xor(cmx, o));
        lt   = min(lt, __shfl_xor(lt, o));
        ht   = max(ht, __shfl_xor(ht, o));
        lp   = min(lp, __shfl_xor(lp, o));
        hp   = max(hp, __shfl_xor(hp, o));
    }

    __shared__ float s_bce[8], s_sm[8], s_mn[8], s_mx[8];
    __shared__ int   s_lt[8], s_ht[8], s_lp[8], s_hp[8];
    if (lane == 0) {
        s_bce[w] = bce; s_sm[w] = sm; s_mn[w] = cmn; s_mx[w] = cmx;
        s_lt[w] = lt; s_ht[w] = ht; s_lp[w] = lp; s_hp[w] = hp;
    }
    __syncthreads();
    if (tid == 0) {
        float B = 0.0f, S = 0.0f, MN = FLT_MAX, MX = -FLT_MAX;
        int LT = LEN, HT = -1, LP = LEN, HP = -1;
        #pragma unroll
        for (int i = 0; i < 8; ++i) {
            B += s_bce[i]; S += s_sm[i];
            MN = fminf(MN, s_mn[i]); MX = fmaxf(MX, s_mx[i]);
            LT = min(LT, s_lt[i]); HT = max(HT, s_ht[i]);
            LP = min(LP, s_lp[i]); HP = max(HP, s_hp[i]);
        }
        const int e = b * BPR + blk;
        bce_blk[e] = B; sm_blk[e] = S;
        cmin_tab[e] = MN; cmax_tab[e] = MX;
        lt_tab[e] = LT; ht_tab[e] = HT;
        lp_tab[e] = LP; hp_tab[e] = HP;
    }
}

// ---------- windowed min/max per (row, which) ----------

__global__ __launch_bounds__(T) void k_rows(
        const float* __restrict__ sig,
        const int* __restrict__ lt_tab, const int* __restrict__ ht_tab,
        const int* __restrict__ lp_tab, const int* __restrict__ hp_tab,
        const float* __restrict__ cmin_tab, const float* __restrict__ cmax_tab,
        float* __restrict__ wmn, float* __restrict__ wmx) {
    const int b     = blockIdx.x;
    const int which = blockIdx.y;          // 0 = target window, 1 = pred window
    const int tid   = threadIdx.x;
    const int* lo_tab = which ? lp_tab : lt_tab;
    const int* hi_tab = which ? hp_tab : ht_tab;

    int lo = LEN, hi = -1;
    for (int c = tid; c < BPR; c += 64) {      // BPR=40 < 64: one step in wave 0
        lo = min(lo, lo_tab[b * BPR + c]);
        hi = max(hi, hi_tab[b * BPR + c]);
    }
    #pragma unroll
    for (int o = 32; o > 0; o >>= 1) {
        lo = min(lo, __shfl_xor(lo, o));
        hi = max(hi, __shfl_xor(hi, o));
    }
    __shared__ int s_lo, s_hi;
    if (tid == 0) { s_lo = lo; s_hi = hi; }
    __syncthreads();
    lo = s_lo; hi = s_hi;

    float mn = FLT_MAX, mx = -FLT_MAX;
    if (lo < LEN) {
        const float* srow = sig + (size_t)b * LEN;
        const int cl = lo / CHUNK, ch = hi / CHUNK;
        const int e1 = (cl == ch) ? hi : cl * CHUNK + CHUNK - 1;
        for (int l = lo + tid; l <= e1; l += T) {
            const float x = srow[l]; mn = fminf(mn, x); mx = fmaxf(mx, x);
        }
        if (ch > cl) {
            for (int l = ch * CHUNK + tid; l <= hi; l += T) {
                const float x = srow[l]; mn = fminf(mn, x); mx = fmaxf(mx, x);
            }
            const float* cmin_row = cmin_tab + b * BPR;
            const float* cmax_row = cmax_tab + b * BPR;
            for (int c = cl + 1 + tid; c < ch; c += T) {
                mn = fminf(mn, cmin_row[c]); mx = fmaxf(mx, cmax_row[c]);
            }
        }
    }
    #pragma unroll
    for (int o = 32; o > 0; o >>= 1) {
        mn = fminf(mn, __shfl_xor(mn, o));
        mx = fmaxf(mx, __shfl_xor(mx, o));
    }
    __shared__ float sh_mn[8], sh_mx[8];
    const int w = tid >> 6, lane = tid & 63;
    if (lane == 0) { sh_mn[w] = mn; sh_mx[w] = mx; }
    __syncthreads();
    if (tid == 0) {
        float MN = FLT_MAX, MX = -FLT_MAX;
        #pragma unroll
        for (int i = 0; i < 8; ++i) {
            MN = fminf(MN, sh_mn[i]); MX = fmaxf(MX, sh_mx[i]);
        }
        if (lo >= LEN) { MN = 1e30f; MX = -1e30f; }   // invalid marker: MX < MN
        wmn[which * BATCH + b] = MN;
        wmx[which * BATCH + b] = MX;
    }
}

// ---------- final combine ----------

__global__ void k_combine(const float* __restrict__ bce_blk,
                          const float* __restrict__ sm_blk,
                          const float* __restrict__ wmn,
                          const float* __restrict__ wmx,
                          float* __restrict__ out) {
    const int tid = threadIdx.x;
    float acc_b = 0.0f, acc_s = 0.0f, acc_a = 0.0f;
    for (int i = tid; i < NSEG; i += 256) { acc_b += bce_blk[i]; acc_s += sm_blk[i]; }
    if (tid < BATCH) {
        const float tmn = wmn[tid],          tmx = wmx[tid];
        const float pmn = wmn[BATCH + tid],  pmx = wmx[BATCH + tid];
        if (tmx >= tmn && pmx >= pmn) {      // both windows valid
            const float ta = tmx - tmn;
            const float pa = pmx - pmn;
            const float d  = fabsf(ta - pa);
            acc_a = (ta > 1e-6f) ? d / (ta + 1e-6f) : d;
        }
    }
    #pragma unroll
    for (int o = 32; o > 0; o >>= 1) {
        acc_b += __shfl_xor(acc_b, o);
        acc_s += __shfl_xor(acc_s, o);
        acc_a += __shfl_xor(acc_a, o);
    }
    __shared__ float sb[4], ss[4], sa[4];
    const int w = tid >> 6, lane = tid & 63;
    if (lane == 0) { sb[w] = acc_b; ss[w] = acc_s; sa[w] = acc_a; }
    __syncthreads();
    if (tid == 0) {
        const double B = (double)(sb[0] + sb[1] + sb[2] + sb[3]);
        const double S = (double)(ss[0] + ss[1] + ss[2] + ss[3]);
        const double A = (double)(sa[0] + sa[1] + sa[2] + sa[3]);
        const double bce = B / ((double)BATCH * (double)LEN);
        const double smo = S / ((double)BATCH * (double)(LEN - 1));
        const double amp = A / (double)BATCH;
        out[0] = (float)(1.0 * bce + 0.5 * amp + 0.3 * smo);
    }
}

// ---------- launch ----------

extern "C" void kernel_launch(void* const* d_in, const int* in_sizes, int n_in,
                              void* d_out, int out_size, void* d_ws, size_t ws_size,
                              hipStream_t stream) {
    const float* signals = (const float*)d_in[0];   // (B, 1, L)
    const float* preds   = (const float*)d_in[1];   // (B, L, 1)
    const float* targs   = (const float*)d_in[2];   // (B, L, 1)
    float* out = (float*)d_out;
    WS w = ws_layout(d_ws);

    dim3 gm(BPR, BATCH);   // 5120 blocks x 8 waves: deep backfill pool
    k_main<<<gm, T, 0, stream>>>(signals, preds, targs,
                                 w.lt_tab, w.ht_tab, w.lp_tab, w.hp_tab,
                                 w.bce_blk, w.sm_blk, w.cmin, w.cmax);

    dim3 gr(BATCH, 2);
    k_rows<<<gr, T, 0, stream>>>(signals,
                                 w.lt_tab, w.ht_tab, w.lp_tab, w.hp_tab,
                                 w.cmin, w.cmax, w.wmn, w.wmx);

    k_combine<<<1, 256, 0, stream>>>(w.bce_blk, w.sm_blk, w.wmn, w.wmx, out);
}

// Round 10
// 43.198 us; speedup vs baseline: 1.2065x; 1.0696x over previous
//
#include <hip/hip_runtime.h>
#include <math.h>
#include <float.h>

#define BATCH 128
#define LEN   100000
#define CHUNK 5000           // elems per segment (LEN % CHUNK == 0)
#define SEGS  (LEN / CHUNK)  // 20 segments per row
#define VPS   (CHUNK / 4)    // 1250 float4 per segment
#define THREADS 512
#define NG    3              // groups per thread: vv = tid + k*512 (k=2 partial)

// ---------- workspace layout ----------
struct WS {
    int*   lt_tab; int* ht_tab; int* lp_tab; int* hp_tab;   // [BATCH*SEGS]
    float* bce_blk; float* sm_blk;                          // [BATCH*SEGS]
    float* cmin; float* cmax;                               // [BATCH*SEGS]
    float* wmn; float* wmx;                                 // [2*BATCH]
};

static inline WS ws_layout(void* d_ws) {
    WS w;
    w.lt_tab  = (int*)d_ws;
    w.ht_tab  = w.lt_tab + BATCH * SEGS;
    w.lp_tab  = w.ht_tab + BATCH * SEGS;
    w.hp_tab  = w.lp_tab + BATCH * SEGS;
    w.bce_blk = (float*)(w.hp_tab + BATCH * SEGS);
    w.sm_blk  = w.bce_blk + BATCH * SEGS;
    w.cmin    = w.sm_blk  + BATCH * SEGS;
    w.cmax    = w.cmin    + BATCH * SEGS;
    w.wmn     = w.cmax    + BATCH * SEGS;
    w.wmx     = w.wmn     + 2 * BATCH;
    return w;
}

// ---------- main fused pass ----------
// RESTORED R4 — the measured optimum of the geometry sweep (43.4 us):
// 2560 blocks (20 segs x 128 rows) x 512 threads, 12 elems/thread.
// R8 (1024 blk, 24 e/t) = 52.1; R9 (5120 blk, 5 e/t) = 46.2 -> this is
// the balance point between backfill depth and per-block overhead.

__global__ __launch_bounds__(THREADS) void k_main(
        const float* __restrict__ sig,
        const float* __restrict__ pred,
        const float* __restrict__ targ,
        int* __restrict__ lt_tab, int* __restrict__ ht_tab,
        int* __restrict__ lp_tab, int* __restrict__ hp_tab,
        float* __restrict__ bce_blk, float* __restrict__ sm_blk,
        float* __restrict__ cmin_tab, float* __restrict__ cmax_tab) {
    const int b   = blockIdx.y;
    const int seg = blockIdx.x;
    const int tid = threadIdx.x;
    const size_t row = (size_t)b * LEN;
    const float* prow = pred + row;
    const float* trow = targ + row;
    const float* srow = sig  + row;
    const int seg0 = seg * CHUNK;
    const bool g2 = (tid < (VPS - 2 * THREADS));   // tid < 226: group 2 valid

    // ---- loads: up to 9 float4 per thread, plain HIP ----
    float4 pv[NG], tv[NG], sv[NG];
    #pragma unroll
    for (int k = 0; k < NG; ++k) {
        if (k < NG - 1 || g2) {
            const int l0 = seg0 + (tid + k * THREADS) * 4;
            pv[k] = *reinterpret_cast<const float4*>(prow + l0);
            tv[k] = *reinterpret_cast<const float4*>(trow + l0);
            sv[k] = *reinterpret_cast<const float4*>(srow + l0);
        }
    }

    // ---- process ----
    float bce = 0.0f, sm = 0.0f;
    float cmn = FLT_MAX, cmx = -FLT_MAX;
    unsigned tmask = 0u, pmask = 0u;

    #pragma unroll
    for (int k = 0; k < NG; ++k) {
        if (k == NG - 1 && !g2) continue;     // only group 2 is partial
        const float4 p4 = pv[k];
        const float4 t4 = tv[k];
        const float4 s4 = sv[k];
        const int l0 = seg0 + (tid + k * THREADS) * 4;
        float sg0, sg1, sg2, sg3;
        #define ONE_ELEM(pp, tt, ss, sgv, BIT) { \
            const float ap = fabsf(pp); \
            const float ee = __expf(-ap); \
            const float zz = 1.0f + ee; \
            const float rr = __builtin_amdgcn_rcpf(zz); \
            bce += fmaxf(pp, 0.0f) - (pp) * (tt) + __logf(zz); \
            sgv = ((pp) >= 0.0f) ? rr : ee * rr; \
            tmask |= ((tt) > 0.5f) ? (1u << (BIT)) : 0u; \
            pmask |= ((pp) > 0.0f) ? (1u << (BIT)) : 0u; \
            cmn = fminf(cmn, (ss)); cmx = fmaxf(cmx, (ss)); }
        ONE_ELEM(p4.x, t4.x, s4.x, sg0, 4 * k + 0)
        ONE_ELEM(p4.y, t4.y, s4.y, sg1, 4 * k + 1)
        ONE_ELEM(p4.z, t4.z, s4.z, sg2, 4 * k + 2)
        ONE_ELEM(p4.w, t4.w, s4.w, sg3, 4 * k + 3)
        #undef ONE_ELEM
        sm += fabsf(sg1 - sg0) + fabsf(sg2 - sg1) + fabsf(sg3 - sg2);
        const float prev3 = __shfl_up(sg3, 1);   // lane-1's sg3 == sigmoid(prow[l0-1])
        if ((tid & 63) == 0) {
            if (l0 > 0) {                        // wave boundary: recompute from load
                const float pp = prow[l0 - 1];
                const float ee = __expf(-fabsf(pp));
                const float rr = __builtin_amdgcn_rcpf(1.0f + ee);
                const float sp = (pp >= 0.0f) ? rr : ee * rr;
                sm += fabsf(sg0 - sp);
            }
        } else {
            sm += fabsf(sg0 - prev3);
        }
    }

    // ---- decode index masks (bit position is monotone in element index) ----
    int lt = LEN, ht = -1, lp = LEN, hp = -1;
    if (tmask) {
        const int f = __ffs(tmask) - 1;
        const int h = 31 - __clz((int)tmask);
        lt = seg0 + (tid + (f >> 2) * THREADS) * 4 + (f & 3);
        ht = seg0 + (tid + (h >> 2) * THREADS) * 4 + (h & 3);
    }
    if (pmask) {
        const int f = __ffs(pmask) - 1;
        const int h = 31 - __clz((int)pmask);
        lp = seg0 + (tid + (f >> 2) * THREADS) * 4 + (f & 3);
        hp = seg0 + (tid + (h >> 2) * THREADS) * 4 + (h & 3);
    }

    // ---- wave reductions ----
    #pragma unroll
    for (int o = 32; o > 0; o >>= 1) {
        bce += __shfl_xor(bce, o);
        sm  += __shfl_xor(sm,  o);
        cmn  = fminf(cmn, __shfl_xor(cmn, o));
        cmx  = fmaxf(cmx, __shfl_xor(cmx, o));
        lt   = min(lt, __shfl_xor(lt, o));
        ht   = max(ht, __shfl_xor(ht, o));
        lp   = min(lp, __shfl_xor(lp, o));
        hp   = max(hp, __shfl_xor(hp, o));
    }

    __shared__ float s_bce[8], s_sm[8], s_mn[8], s_mx[8];
    __shared__ int   s_lt[8], s_ht[8], s_lp[8], s_hp[8];
    const int w = tid >> 6, lane = tid & 63;
    if (lane == 0) {
        s_bce[w] = bce; s_sm[w] = sm; s_mn[w] = cmn; s_mx[w] = cmx;
        s_lt[w] = lt; s_ht[w] = ht; s_lp[w] = lp; s_hp[w] = hp;
    }
    __syncthreads();
    if (tid == 0) {
        float B = 0.0f, S = 0.0f, MN = FLT_MAX, MX = -FLT_MAX;
        int LT = LEN, HT = -1, LP = LEN, HP = -1;
        #pragma unroll
        for (int i = 0; i < 8; ++i) {
            B += s_bce[i]; S += s_sm[i];
            MN = fminf(MN, s_mn[i]); MX = fmaxf(MX, s_mx[i]);
            LT = min(LT, s_lt[i]); HT = max(HT, s_ht[i]);
            LP = min(LP, s_lp[i]); HP = max(HP, s_hp[i]);
        }
        const int e = b * SEGS + seg;
        bce_blk[e] = B; sm_blk[e] = S;
        cmin_tab[e] = MN; cmax_tab[e] = MX;
        lt_tab[e] = LT; ht_tab[e] = HT;
        lp_tab[e] = LP; hp_tab[e] = HP;
    }
}

// ---------- windowed min/max per (row, which) ----------

__global__ __launch_bounds__(THREADS) void k_rows(
        const float* __restrict__ sig,
        const int* __restrict__ lt_tab, const int* __restrict__ ht_tab,
        const int* __restrict__ lp_tab, const int* __restrict__ hp_tab,
        const float* __restrict__ cmin_tab, const float* __restrict__ cmax_tab,
        float* __restrict__ wmn, float* __restrict__ wmx) {
    const int b     = blockIdx.x;
    const int which = blockIdx.y;          // 0 = target window, 1 = pred window
    const int tid   = threadIdx.x;
    const int* lo_tab = which ? lp_tab : lt_tab;
    const int* hi_tab = which ? hp_tab : ht_tab;

    // derive row lo/hi from the SEGS per-segment entries (wave 0 computes)
    int lo = LEN, hi = -1;
    if (tid < SEGS) { lo = lo_tab[b * SEGS + tid]; hi = hi_tab[b * SEGS + tid]; }
    #pragma unroll
    for (int o = 32; o > 0; o >>= 1) {
        lo = min(lo, __shfl_xor(lo, o));
        hi = max(hi, __shfl_xor(hi, o));
    }
    __shared__ int s_lo, s_hi;
    if (tid == 0) { s_lo = lo; s_hi = hi; }
    __syncthreads();
    lo = s_lo; hi = s_hi;

    float mn = FLT_MAX, mx = -FLT_MAX;
    if (lo < LEN) {
        const float* srow = sig + (size_t)b * LEN;
        const int cl = lo / CHUNK, ch = hi / CHUNK;
        const int e1 = (cl == ch) ? hi : cl * CHUNK + CHUNK - 1;
        for (int l = lo + tid; l <= e1; l += THREADS) {
            const float x = srow[l]; mn = fminf(mn, x); mx = fmaxf(mx, x);
        }
        if (ch > cl) {
            for (int l = ch * CHUNK + tid; l <= hi; l += THREADS) {
                const float x = srow[l]; mn = fminf(mn, x); mx = fmaxf(mx, x);
            }
            const float* cmin_row = cmin_tab + b * SEGS;
            const float* cmax_row = cmax_tab + b * SEGS;
            for (int c = cl + 1 + tid; c < ch; c += THREADS) {
                mn = fminf(mn, cmin_row[c]); mx = fmaxf(mx, cmax_row[c]);
            }
        }
    }
    #pragma unroll
    for (int o = 32; o > 0; o >>= 1) {
        mn = fminf(mn, __shfl_xor(mn, o));
        mx = fmaxf(mx, __shfl_xor(mx, o));
    }
    __shared__ float sh_mn[8], sh_mx[8];
    const int w = tid >> 6, lane = tid & 63;
    if (lane == 0) { sh_mn[w] = mn; sh_mx[w] = mx; }
    __syncthreads();
    if (tid == 0) {
        float MN = FLT_MAX, MX = -FLT_MAX;
        #pragma unroll
        for (int i = 0; i < 8; ++i) {
            MN = fminf(MN, sh_mn[i]); MX = fmaxf(MX, sh_mx[i]);
        }
        if (lo >= LEN) { MN = 1e30f; MX = -1e30f; }   // invalid marker: MX < MN
        wmn[which * BATCH + b] = MN;
        wmx[which * BATCH + b] = MX;
    }
}

// ---------- final combine ----------

__global__ void k_combine(const float* __restrict__ bce_blk,
                          const float* __restrict__ sm_blk,
                          const float* __restrict__ wmn,
                          const float* __restrict__ wmx,
                          float* __restrict__ out) {
    const int tid = threadIdx.x;
    float acc_b = 0.0f, acc_s = 0.0f, acc_a = 0.0f;
    for (int i = tid; i < BATCH * SEGS; i += 256) { acc_b += bce_blk[i]; acc_s += sm_blk[i]; }
    if (tid < BATCH) {
        const float tmn = wmn[tid],          tmx = wmx[tid];
        const float pmn = wmn[BATCH + tid],  pmx = wmx[BATCH + tid];
        if (tmx >= tmn && pmx >= pmn) {      // both windows valid
            const float ta = tmx - tmn;
            const float pa = pmx - pmn;
            const float d  = fabsf(ta - pa);
            acc_a = (ta > 1e-6f) ? d / (ta + 1e-6f) : d;
        }
    }
    #pragma unroll
    for (int o = 32; o > 0; o >>= 1) {
        acc_b += __shfl_xor(acc_b, o);
        acc_s += __shfl_xor(acc_s, o);
        acc_a += __shfl_xor(acc_a, o);
    }
    __shared__ float sb[4], ss[4], sa[4];
    const int w = tid >> 6, lane = tid & 63;
    if (lane == 0) { sb[w] = acc_b; ss[w] = acc_s; sa[w] = acc_a; }
    __syncthreads();
    if (tid == 0) {
        const double B = (double)(sb[0] + sb[1] + sb[2] + sb[3]);
        const double S = (double)(ss[0] + ss[1] + ss[2] + ss[3]);
        const double A = (double)(sa[0] + sa[1] + sa[2] + sa[3]);
        const double bce = B / ((double)BATCH * (double)LEN);
        const double smo = S / ((double)BATCH * (double)(LEN - 1));
        const double amp = A / (double)BATCH;
        out[0] = (float)(1.0 * bce + 0.5 * amp + 0.3 * smo);
    }
}

// ---------- launch ----------

extern "C" void kernel_launch(void* const* d_in, const int* in_sizes, int n_in,
                              void* d_out, int out_size, void* d_ws, size_t ws_size,
                              hipStream_t stream) {
    const float* signals = (const float*)d_in[0];   // (B, 1, L)
    const float* preds   = (const float*)d_in[1];   // (B, L, 1)
    const float* targs   = (const float*)d_in[2];   // (B, L, 1)
    float* out = (float*)d_out;
    WS w = ws_layout(d_ws);

    dim3 gm(SEGS, BATCH);                // 2560 blocks x 8 waves: the optimum
    k_main<<<gm, THREADS, 0, stream>>>(signals, preds, targs,
                                       w.lt_tab, w.ht_tab, w.lp_tab, w.hp_tab,
                                       w.bce_blk, w.sm_blk, w.cmin, w.cmax);

    dim3 gr(BATCH, 2);
    k_rows<<<gr, THREADS, 0, stream>>>(signals,
                                       w.lt_tab, w.ht_tab, w.lp_tab, w.hp_tab,
                                       w.cmin, w.cmax, w.wmn, w.wmx);

    k_combine<<<1, 256, 0, stream>>>(w.bce_blk, w.sm_blk, w.wmn, w.wmx, out);
}